// Round 1
// baseline (610.765 us; speedup 1.0000x reference)
//
#include <hip/hip_runtime.h>

// ---------------- CSR construction ----------------

__global__ void count_kernel(const int* __restrict__ dst, int* __restrict__ cnt, int E) {
    int e = blockIdx.x * blockDim.x + threadIdx.x;
    if (e < E) atomicAdd(&cnt[dst[e]], 1);
}

__global__ void scan1(const int* __restrict__ cnt, int* __restrict__ offs,
                      int* __restrict__ partials, int N) {
    __shared__ int s[256];
    int t = threadIdx.x;
    int i = blockIdx.x * 256 + t;
    int v = (i < N) ? cnt[i] : 0;
    s[t] = v;
    __syncthreads();
    #pragma unroll
    for (int d = 1; d < 256; d <<= 1) {
        int tv = (t >= d) ? s[t - d] : 0;
        __syncthreads();
        s[t] += tv;
        __syncthreads();
    }
    if (i < N) offs[i] = s[t] - v;   // block-local exclusive
    if (t == 255) partials[blockIdx.x] = s[255];
}

__global__ void scan2(int* partials, int nb) {
    __shared__ int s[256];
    int t = threadIdx.x;
    int v = (t < nb) ? partials[t] : 0;
    s[t] = v;
    __syncthreads();
    #pragma unroll
    for (int d = 1; d < 256; d <<= 1) {
        int tv = (t >= d) ? s[t - d] : 0;
        __syncthreads();
        s[t] += tv;
        __syncthreads();
    }
    if (t < nb) partials[t] = s[t] - v;  // exclusive block bases
}

__global__ void scan3(const int* __restrict__ cnt, int* __restrict__ offs,
                      int* __restrict__ offwork, float* __restrict__ dinv,
                      const int* __restrict__ partials, int N, int E) {
    int i = blockIdx.x * 256 + threadIdx.x;
    if (i < N) {
        int o = offs[i] + partials[blockIdx.x];
        offs[i] = o;
        offwork[i] = o;
        dinv[i] = rsqrtf((float)cnt[i] + 1.0f);  // deg = in-degree + self-loop
    }
    if (i == 0) offs[N] = E;
}

__global__ void scatter_kernel(const int* __restrict__ src, const int* __restrict__ dst,
                               int* __restrict__ offwork, int* __restrict__ csr, int E) {
    int e = blockIdx.x * blockDim.x + threadIdx.x;
    if (e < E) {
        int pos = atomicAdd(&offwork[dst[e]], 1);
        csr[pos] = src[e];
    }
}

// ---------------- fp32 GEMM: Y[M,128] = X[M,128] @ W[128,128] (+bias, relu) ----------------
// BM=64, BN=128, BK=32, 256 threads, thread tile 4 rows x 8 cols.

__global__ __launch_bounds__(256, 2) void gemm128(const float* __restrict__ X,
                                                  const float* __restrict__ W,
                                                  const float* __restrict__ bias,
                                                  float* __restrict__ Y,
                                                  int M, int relu) {
    __shared__ float As[32][68];    // k-major: As[k][row], padded for align+banks
    __shared__ float Bs[32][132];   // Bs[k][col]

    int tid = threadIdx.x;
    int tx = tid & 15;       // col group 0..15
    int ty = tid >> 4;       // row group 0..15
    int row0 = blockIdx.x * 64;

    float acc[4][8];
    #pragma unroll
    for (int r = 0; r < 4; r++)
        #pragma unroll
        for (int c = 0; c < 8; c++) acc[r][c] = 0.0f;

    int lr = tid >> 2;            // 0..63: X tile row
    int kc = (tid & 3) * 8;       // k chunk within tile
    int wr = tid >> 3;            // 0..31: W k-row
    int wc = (tid & 7) * 16;      // W col chunk

    for (int k0 = 0; k0 < 128; k0 += 32) {
        // stage loads in registers
        float4 xa, xb;
        int grow = row0 + lr;
        if (grow < M) {
            xa = *(const float4*)&X[grow * 128 + k0 + kc];
            xb = *(const float4*)&X[grow * 128 + k0 + kc + 4];
        } else {
            xa = make_float4(0.f, 0.f, 0.f, 0.f);
            xb = make_float4(0.f, 0.f, 0.f, 0.f);
        }
        float4 w0 = *(const float4*)&W[(k0 + wr) * 128 + wc + 0];
        float4 w1 = *(const float4*)&W[(k0 + wr) * 128 + wc + 4];
        float4 w2 = *(const float4*)&W[(k0 + wr) * 128 + wc + 8];
        float4 w3 = *(const float4*)&W[(k0 + wr) * 128 + wc + 12];

        __syncthreads();  // previous iteration's compute done
        As[kc + 0][lr] = xa.x; As[kc + 1][lr] = xa.y;
        As[kc + 2][lr] = xa.z; As[kc + 3][lr] = xa.w;
        As[kc + 4][lr] = xb.x; As[kc + 5][lr] = xb.y;
        As[kc + 6][lr] = xb.z; As[kc + 7][lr] = xb.w;
        *(float4*)&Bs[wr][wc + 0]  = w0;
        *(float4*)&Bs[wr][wc + 4]  = w1;
        *(float4*)&Bs[wr][wc + 8]  = w2;
        *(float4*)&Bs[wr][wc + 12] = w3;
        __syncthreads();

        #pragma unroll
        for (int k = 0; k < 32; k++) {
            float4 a   = *(const float4*)&As[k][ty * 4];
            float4 bb0 = *(const float4*)&Bs[k][tx * 4];
            float4 bb1 = *(const float4*)&Bs[k][64 + tx * 4];
            float av[4] = {a.x, a.y, a.z, a.w};
            float bv[8] = {bb0.x, bb0.y, bb0.z, bb0.w, bb1.x, bb1.y, bb1.z, bb1.w};
            #pragma unroll
            for (int r = 0; r < 4; r++)
                #pragma unroll
                for (int c = 0; c < 8; c++)
                    acc[r][c] = fmaf(av[r], bv[c], acc[r][c]);
        }
    }

    #pragma unroll
    for (int r = 0; r < 4; r++) {
        int grow = row0 + ty * 4 + r;
        if (grow < M) {
            float o[8];
            #pragma unroll
            for (int c = 0; c < 8; c++) o[c] = acc[r][c];
            if (bias) {
                #pragma unroll
                for (int c = 0; c < 4; c++) {
                    o[c]     += bias[tx * 4 + c];
                    o[c + 4] += bias[64 + tx * 4 + c];
                }
            }
            if (relu) {
                #pragma unroll
                for (int c = 0; c < 8; c++) o[c] = fmaxf(o[c], 0.0f);
            }
            float4 o0 = make_float4(o[0], o[1], o[2], o[3]);
            float4 o1 = make_float4(o[4], o[5], o[6], o[7]);
            *(float4*)&Y[grow * 128 + tx * 4]      = o0;
            *(float4*)&Y[grow * 128 + 64 + tx * 4] = o1;
        }
    }
}

// ---------------- aggregations (CSR gather, no atomics) ----------------

// GCN: B[v] = relu( dinv[v] * ( sum_{s in N_in(v)} A[s]*dinv[s] + A[v]*dinv[v] ) + b0 )
__global__ void gcn_agg(const float* __restrict__ A, float* __restrict__ B,
                        const int* __restrict__ offs, const int* __restrict__ csr,
                        const float* __restrict__ dinv, const float* __restrict__ b0) {
    int v = blockIdx.x;
    int f = threadIdx.x;
    float dv = dinv[v];
    float acc = A[v * 128 + f] * dv;
    int i0 = offs[v], i1 = offs[v + 1];
    for (int i = i0; i < i1; i++) {
        int s = csr[i];
        acc += A[s * 128 + f] * dinv[s];
    }
    float r = acc * dv + b0[f];
    B[v * 128 + f] = fmaxf(r, 0.0f);
}

// GIN pre-linear: U[v] = H[v] + sum_{s in N_in(v)} H[s]
__global__ void gin_agg(const float* __restrict__ H, float* __restrict__ U,
                        const int* __restrict__ offs, const int* __restrict__ csr) {
    int v = blockIdx.x;
    int f = threadIdx.x;
    float acc = H[v * 128 + f];
    int i0 = offs[v], i1 = offs[v + 1];
    for (int i = i0; i < i1; i++) {
        acc += H[csr[i] * 128 + f];
    }
    U[v * 128 + f] = acc;
}

// ---------------- pooling + head ----------------

__global__ void graph_bounds(const int* __restrict__ batch, int* __restrict__ gstart,
                             int N, int G) {
    int g = blockIdx.x * blockDim.x + threadIdx.x;
    if (g > G) return;
    int lo = 0, hi = N;
    while (lo < hi) {
        int mid = (lo + hi) >> 1;
        if (batch[mid] < g) lo = mid + 1; else hi = mid;
    }
    gstart[g] = lo;
}

__global__ void pool_kernel(const float* __restrict__ H, const int* __restrict__ gstart,
                            float* __restrict__ Mout) {
    int g = blockIdx.x;
    int f = threadIdx.x;
    int s = gstart[g], e = gstart[g + 1];
    float acc = 0.0f;
    for (int i = s; i < e; i++) acc += H[i * 128 + f];
    int n = e - s;
    Mout[g * 128 + f] = acc / (float)(n > 0 ? n : 1);
}

// g = relu(M @ Wh1 + bh1):  [G,128] @ [128,256]
__global__ void head1(const float* __restrict__ Mx, const float* __restrict__ W,
                      const float* __restrict__ b, float* __restrict__ Y) {
    __shared__ float m[128];
    int g = blockIdx.x;
    int j = threadIdx.x;  // 256
    if (j < 128) m[j] = Mx[g * 128 + j];
    __syncthreads();
    float acc = b[j];
    for (int k = 0; k < 128; k++) acc = fmaf(m[k], W[k * 256 + j], acc);
    Y[g * 256 + j] = fmaxf(acc, 0.0f);
}

// out = g @ Wh2 + bh2:  [G,256] @ [256,128]
__global__ void head2(const float* __restrict__ Gx, const float* __restrict__ W,
                      const float* __restrict__ b, float* __restrict__ out) {
    __shared__ float m[256];
    int g = blockIdx.x;
    int j = threadIdx.x;  // 128
    m[j] = Gx[g * 256 + j];
    m[j + 128] = Gx[g * 256 + 128 + j];
    __syncthreads();
    float acc = b[j];
    for (int k = 0; k < 256; k++) acc = fmaf(m[k], W[k * 128 + j], acc);
    out[g * 128 + j] = acc;
}

// ---------------- launch ----------------

extern "C" void kernel_launch(void* const* d_in, const int* in_sizes, int n_in,
                              void* d_out, int out_size, void* d_ws, size_t ws_size,
                              hipStream_t stream) {
    const float* x     = (const float*)d_in[0];
    const int*   ei    = (const int*)d_in[1];
    const int*   batch = (const int*)d_in[2];
    const float* W0  = (const float*)d_in[3];
    const float* b0  = (const float*)d_in[4];
    const float* Wg1 = (const float*)d_in[5];
    const float* bg1 = (const float*)d_in[6];
    const float* Wg2 = (const float*)d_in[7];
    const float* bg2 = (const float*)d_in[8];
    const float* Wh1 = (const float*)d_in[9];
    const float* bh1 = (const float*)d_in[10];
    const float* Wh2 = (const float*)d_in[11];
    const float* bh2 = (const float*)d_in[12];

    int N = in_sizes[2];          // batch has N elements
    int E = in_sizes[1] / 2;      // edge_index is (2,E)
    int G = out_size / 128;       // output is (G, 128)
    const int* srcp = ei;
    const int* dstp = ei + E;

    // workspace carve (256B aligned)
    char* w = (char*)d_ws;
    auto take = [&](size_t bytes) -> void* {
        void* p = (void*)w;
        w += (bytes + 255) & ~(size_t)255;
        return p;
    };
    float* A        = (float*)take((size_t)N * 128 * 4);
    float* Bf       = (float*)take((size_t)N * 128 * 4);
    int*   csr      = (int*)take((size_t)E * 4);
    int*   offs     = (int*)take((size_t)(N + 1) * 4);
    int*   offw     = (int*)take((size_t)N * 4);
    int*   cnt      = (int*)take((size_t)N * 4);
    float* dinv     = (float*)take((size_t)N * 4);
    int*   partials = (int*)take(1024);
    int*   gstart   = (int*)take((size_t)(G + 1) * 4);
    float* Mg       = (float*)take((size_t)G * 128 * 4);
    float* Gh       = (float*)take((size_t)G * 256 * 4);

    int nb = (N + 255) / 256;

    // CSR build
    hipMemsetAsync(cnt, 0, (size_t)N * 4, stream);
    count_kernel<<<(E + 255) / 256, 256, 0, stream>>>(dstp, cnt, E);
    scan1<<<nb, 256, 0, stream>>>(cnt, offs, partials, N);
    scan2<<<1, 256, 0, stream>>>(partials, nb);
    scan3<<<nb, 256, 0, stream>>>(cnt, offs, offw, dinv, partials, N, E);
    scatter_kernel<<<(E + 255) / 256, 256, 0, stream>>>(srcp, dstp, offw, csr, E);

    // GCN: A = x@W0 ; B = relu(norm-agg(A) + b0)
    gemm128<<<(N + 63) / 64, 256, 0, stream>>>(x, W0, nullptr, A, N, 0);
    gcn_agg<<<N, 128, 0, stream>>>(A, Bf, offs, csr, dinv, b0);

    // GIN 1
    gin_agg<<<N, 128, 0, stream>>>(Bf, A, offs, csr);
    gemm128<<<(N + 63) / 64, 256, 0, stream>>>(A, Wg1, bg1, Bf, N, 1);

    // GIN 2
    gin_agg<<<N, 128, 0, stream>>>(Bf, A, offs, csr);
    gemm128<<<(N + 63) / 64, 256, 0, stream>>>(A, Wg2, bg2, Bf, N, 1);

    // pool + head
    graph_bounds<<<(G + 1 + 255) / 256, 256, 0, stream>>>(batch, gstart, N, G);
    pool_kernel<<<G, 128, 0, stream>>>(Bf, gstart, Mg);
    head1<<<G, 256, 0, stream>>>(Mg, Wh1, bh1, Gh);
    head2<<<G, 128, 0, stream>>>(Gh, Wh2, bh2, (float*)d_out);
}

// Round 2
// 514.843 us; speedup vs baseline: 1.1863x; 1.1863x over previous
//
#include <hip/hip_runtime.h>

// ---------------- CSR construction ----------------

__global__ void count_kernel(const int* __restrict__ dst, int* __restrict__ cnt, int E) {
    int e = blockIdx.x * blockDim.x + threadIdx.x;
    if (e < E) atomicAdd(&cnt[dst[e]], 1);
}

__global__ void scan1(const int* __restrict__ cnt, int* __restrict__ offs,
                      int* __restrict__ partials, int N) {
    __shared__ int s[256];
    int t = threadIdx.x;
    int i = blockIdx.x * 256 + t;
    int v = (i < N) ? cnt[i] : 0;
    s[t] = v;
    __syncthreads();
    #pragma unroll
    for (int d = 1; d < 256; d <<= 1) {
        int tv = (t >= d) ? s[t - d] : 0;
        __syncthreads();
        s[t] += tv;
        __syncthreads();
    }
    if (i < N) offs[i] = s[t] - v;   // block-local exclusive
    if (t == 255) partials[blockIdx.x] = s[255];
}

__global__ void scan2(int* partials, int nb) {
    __shared__ int s[256];
    int t = threadIdx.x;
    int v = (t < nb) ? partials[t] : 0;
    s[t] = v;
    __syncthreads();
    #pragma unroll
    for (int d = 1; d < 256; d <<= 1) {
        int tv = (t >= d) ? s[t - d] : 0;
        __syncthreads();
        s[t] += tv;
        __syncthreads();
    }
    if (t < nb) partials[t] = s[t] - v;  // exclusive block bases
}

__global__ void scan3(const int* __restrict__ cnt, int* __restrict__ offs,
                      int* __restrict__ offwork, float* __restrict__ dinv,
                      const int* __restrict__ partials, int N, int E) {
    int i = blockIdx.x * 256 + threadIdx.x;
    if (i < N) {
        int o = offs[i] + partials[blockIdx.x];
        offs[i] = o;
        offwork[i] = o;
        dinv[i] = rsqrtf((float)cnt[i] + 1.0f);  // deg = in-degree + self-loop
    }
    if (i == 0) offs[N] = E;
}

__global__ void scatter_kernel(const int* __restrict__ src, const int* __restrict__ dst,
                               int* __restrict__ offwork, int* __restrict__ csr, int E) {
    int e = blockIdx.x * blockDim.x + threadIdx.x;
    if (e < E) {
        int pos = atomicAdd(&offwork[dst[e]], 1);
        csr[pos] = src[e];
    }
}

// ---------------- fp32 GEMM: Y[M,128] = X[M,128] @ W[128,128] (+bias, relu, rowscale) ----
// BM=64, BN=128, BK=32, 256 threads, thread tile 4 rows x 8 cols.

__global__ __launch_bounds__(256, 2) void gemm128(const float* __restrict__ X,
                                                  const float* __restrict__ W,
                                                  const float* __restrict__ bias,
                                                  const float* __restrict__ rowscale,
                                                  float* __restrict__ Y,
                                                  int M, int relu) {
    __shared__ float As[32][68];    // k-major: As[k][row]
    __shared__ float Bs[32][132];   // Bs[k][col]

    int tid = threadIdx.x;
    int tx = tid & 15;       // col group 0..15
    int ty = tid >> 4;       // row group 0..15
    int row0 = blockIdx.x * 64;

    float acc[4][8];
    #pragma unroll
    for (int r = 0; r < 4; r++)
        #pragma unroll
        for (int c = 0; c < 8; c++) acc[r][c] = 0.0f;

    int lr = tid >> 2;            // 0..63: X tile row
    int kc = (tid & 3) * 8;       // k chunk within tile
    int wr = tid >> 3;            // 0..31: W k-row
    int wc = (tid & 7) * 16;      // W col chunk

    for (int k0 = 0; k0 < 128; k0 += 32) {
        float4 xa, xb;
        int grow = row0 + lr;
        if (grow < M) {
            xa = *(const float4*)&X[grow * 128 + k0 + kc];
            xb = *(const float4*)&X[grow * 128 + k0 + kc + 4];
        } else {
            xa = make_float4(0.f, 0.f, 0.f, 0.f);
            xb = make_float4(0.f, 0.f, 0.f, 0.f);
        }
        float4 w0 = *(const float4*)&W[(k0 + wr) * 128 + wc + 0];
        float4 w1 = *(const float4*)&W[(k0 + wr) * 128 + wc + 4];
        float4 w2 = *(const float4*)&W[(k0 + wr) * 128 + wc + 8];
        float4 w3 = *(const float4*)&W[(k0 + wr) * 128 + wc + 12];

        __syncthreads();
        As[kc + 0][lr] = xa.x; As[kc + 1][lr] = xa.y;
        As[kc + 2][lr] = xa.z; As[kc + 3][lr] = xa.w;
        As[kc + 4][lr] = xb.x; As[kc + 5][lr] = xb.y;
        As[kc + 6][lr] = xb.z; As[kc + 7][lr] = xb.w;
        *(float4*)&Bs[wr][wc + 0]  = w0;
        *(float4*)&Bs[wr][wc + 4]  = w1;
        *(float4*)&Bs[wr][wc + 8]  = w2;
        *(float4*)&Bs[wr][wc + 12] = w3;
        __syncthreads();

        #pragma unroll
        for (int k = 0; k < 32; k++) {
            float4 a   = *(const float4*)&As[k][ty * 4];
            float4 bb0 = *(const float4*)&Bs[k][tx * 4];
            float4 bb1 = *(const float4*)&Bs[k][64 + tx * 4];
            float av[4] = {a.x, a.y, a.z, a.w};
            float bv[8] = {bb0.x, bb0.y, bb0.z, bb0.w, bb1.x, bb1.y, bb1.z, bb1.w};
            #pragma unroll
            for (int r = 0; r < 4; r++)
                #pragma unroll
                for (int c = 0; c < 8; c++)
                    acc[r][c] = fmaf(av[r], bv[c], acc[r][c]);
        }
    }

    #pragma unroll
    for (int r = 0; r < 4; r++) {
        int grow = row0 + ty * 4 + r;
        if (grow < M) {
            float scale = rowscale ? rowscale[grow] : 1.0f;
            float o[8];
            #pragma unroll
            for (int c = 0; c < 8; c++) o[c] = acc[r][c];
            if (bias) {
                #pragma unroll
                for (int c = 0; c < 4; c++) {
                    o[c]     += bias[tx * 4 + c];
                    o[c + 4] += bias[64 + tx * 4 + c];
                }
            }
            #pragma unroll
            for (int c = 0; c < 8; c++) o[c] *= scale;
            if (relu) {
                #pragma unroll
                for (int c = 0; c < 8; c++) o[c] = fmaxf(o[c], 0.0f);
            }
            float4 o0 = make_float4(o[0], o[1], o[2], o[3]);
            float4 o1 = make_float4(o[4], o[5], o[6], o[7]);
            *(float4*)&Y[grow * 128 + tx * 4]      = o0;
            *(float4*)&Y[grow * 128 + 64 + tx * 4] = o1;
        }
    }
}

// ---------------- aggregations (CSR gather, no atomics, 4-way ILP) ----------------

// GCN epilogue-agg on pre-scaled A' = (x@W0)*dinv:
// B[v] = relu( (A'[v] + sum_{s in N_in(v)} A'[s]) * dinv[v] + b0 )
__global__ void gcn_agg(const float* __restrict__ A, float* __restrict__ B,
                        const int* __restrict__ offs, const int* __restrict__ csr,
                        const float* __restrict__ dinv, const float* __restrict__ b0) {
    int v = blockIdx.x;
    int f = threadIdx.x;
    float acc = A[v * 128 + f];
    int i0 = offs[v], i1 = offs[v + 1];
    int i = i0;
    for (; i + 4 <= i1; i += 4) {
        int s0 = csr[i + 0];
        int s1 = csr[i + 1];
        int s2 = csr[i + 2];
        int s3 = csr[i + 3];
        float a0 = A[s0 * 128 + f];
        float a1 = A[s1 * 128 + f];
        float a2 = A[s2 * 128 + f];
        float a3 = A[s3 * 128 + f];
        acc += a0;
        acc += a1;
        acc += a2;
        acc += a3;
    }
    for (; i < i1; i++) acc += A[csr[i] * 128 + f];
    float r = acc * dinv[v] + b0[f];
    B[v * 128 + f] = fmaxf(r, 0.0f);
}

// GIN pre-linear: U[v] = H[v] + sum_{s in N_in(v)} H[s]
__global__ void gin_agg(const float* __restrict__ H, float* __restrict__ U,
                        const int* __restrict__ offs, const int* __restrict__ csr) {
    int v = blockIdx.x;
    int f = threadIdx.x;
    float acc = H[v * 128 + f];
    int i0 = offs[v], i1 = offs[v + 1];
    int i = i0;
    for (; i + 4 <= i1; i += 4) {
        int s0 = csr[i + 0];
        int s1 = csr[i + 1];
        int s2 = csr[i + 2];
        int s3 = csr[i + 3];
        float a0 = H[s0 * 128 + f];
        float a1 = H[s1 * 128 + f];
        float a2 = H[s2 * 128 + f];
        float a3 = H[s3 * 128 + f];
        acc += a0;
        acc += a1;
        acc += a2;
        acc += a3;
    }
    for (; i < i1; i++) acc += H[csr[i] * 128 + f];
    U[v * 128 + f] = acc;
}

// ---------------- pooling + head ----------------

__global__ void graph_bounds(const int* __restrict__ batch, int* __restrict__ gstart,
                             int N, int G) {
    int g = blockIdx.x * blockDim.x + threadIdx.x;
    if (g > G) return;
    int lo = 0, hi = N;
    while (lo < hi) {
        int mid = (lo + hi) >> 1;
        if (batch[mid] < g) lo = mid + 1; else hi = mid;
    }
    gstart[g] = lo;
}

__global__ void pool_kernel(const float* __restrict__ H, const int* __restrict__ gstart,
                            float* __restrict__ Mout) {
    int g = blockIdx.x;
    int f = threadIdx.x;
    int s = gstart[g], e = gstart[g + 1];
    float acc = 0.0f;
    for (int i = s; i < e; i++) acc += H[i * 128 + f];
    int n = e - s;
    Mout[g * 128 + f] = acc / (float)(n > 0 ? n : 1);
}

// g = relu(M @ Wh1 + bh1):  [G,128] @ [128,256]
__global__ void head1(const float* __restrict__ Mx, const float* __restrict__ W,
                      const float* __restrict__ b, float* __restrict__ Y) {
    __shared__ float m[128];
    int g = blockIdx.x;
    int j = threadIdx.x;  // 256
    if (j < 128) m[j] = Mx[g * 128 + j];
    __syncthreads();
    float acc = b[j];
    for (int k = 0; k < 128; k++) acc = fmaf(m[k], W[k * 256 + j], acc);
    Y[g * 256 + j] = fmaxf(acc, 0.0f);
}

// out = g @ Wh2 + bh2:  [G,256] @ [256,128]
__global__ void head2(const float* __restrict__ Gx, const float* __restrict__ W,
                      const float* __restrict__ b, float* __restrict__ out) {
    __shared__ float m[256];
    int g = blockIdx.x;
    int j = threadIdx.x;  // 128
    m[j] = Gx[g * 256 + j];
    m[j + 128] = Gx[g * 256 + 128 + j];
    __syncthreads();
    float acc = b[j];
    for (int k = 0; k < 256; k++) acc = fmaf(m[k], W[k * 128 + j], acc);
    out[g * 128 + j] = acc;
}

// ---------------- launch ----------------

extern "C" void kernel_launch(void* const* d_in, const int* in_sizes, int n_in,
                              void* d_out, int out_size, void* d_ws, size_t ws_size,
                              hipStream_t stream) {
    const float* x     = (const float*)d_in[0];
    const int*   ei    = (const int*)d_in[1];
    const int*   batch = (const int*)d_in[2];
    const float* W0  = (const float*)d_in[3];
    const float* b0  = (const float*)d_in[4];
    const float* Wg1 = (const float*)d_in[5];
    const float* bg1 = (const float*)d_in[6];
    const float* Wg2 = (const float*)d_in[7];
    const float* bg2 = (const float*)d_in[8];
    const float* Wh1 = (const float*)d_in[9];
    const float* bh1 = (const float*)d_in[10];
    const float* Wh2 = (const float*)d_in[11];
    const float* bh2 = (const float*)d_in[12];

    int N = in_sizes[2];          // batch has N elements
    int E = in_sizes[1] / 2;      // edge_index is (2,E)
    int G = out_size / 128;       // output is (G, 128)
    const int* srcp = ei;
    const int* dstp = ei + E;

    // workspace carve (256B aligned)
    char* w = (char*)d_ws;
    auto take = [&](size_t bytes) -> void* {
        void* p = (void*)w;
        w += (bytes + 255) & ~(size_t)255;
        return p;
    };
    float* A        = (float*)take((size_t)N * 128 * 4);
    float* Bf       = (float*)take((size_t)N * 128 * 4);
    int*   csr      = (int*)take((size_t)E * 4);
    int*   offs     = (int*)take((size_t)(N + 1) * 4);
    int*   offw     = (int*)take((size_t)N * 4);
    int*   cnt      = (int*)take((size_t)N * 4);
    float* dinv     = (float*)take((size_t)N * 4);
    int*   partials = (int*)take(1024);
    int*   gstart   = (int*)take((size_t)(G + 1) * 4);
    float* Mg       = (float*)take((size_t)G * 128 * 4);
    float* Gh       = (float*)take((size_t)G * 256 * 4);

    int nb = (N + 255) / 256;

    // CSR build
    hipMemsetAsync(cnt, 0, (size_t)N * 4, stream);
    count_kernel<<<(E + 255) / 256, 256, 0, stream>>>(dstp, cnt, E);
    scan1<<<nb, 256, 0, stream>>>(cnt, offs, partials, N);
    scan2<<<1, 256, 0, stream>>>(partials, nb);
    scan3<<<nb, 256, 0, stream>>>(cnt, offs, offw, dinv, partials, N, E);
    scatter_kernel<<<(E + 255) / 256, 256, 0, stream>>>(srcp, dstp, offw, csr, E);

    // GCN: A = (x@W0) * dinv[row] ; B = relu((A[v]+sum A[nbr]) * dinv[v] + b0)
    gemm128<<<(N + 63) / 64, 256, 0, stream>>>(x, W0, nullptr, dinv, A, N, 0);
    gcn_agg<<<N, 128, 0, stream>>>(A, Bf, offs, csr, dinv, b0);

    // GIN 1
    gin_agg<<<N, 128, 0, stream>>>(Bf, A, offs, csr);
    gemm128<<<(N + 63) / 64, 256, 0, stream>>>(A, Wg1, bg1, nullptr, Bf, N, 1);

    // GIN 2
    gin_agg<<<N, 128, 0, stream>>>(Bf, A, offs, csr);
    gemm128<<<(N + 63) / 64, 256, 0, stream>>>(A, Wg2, bg2, nullptr, Bf, N, 1);

    // pool + head
    graph_bounds<<<(G + 1 + 255) / 256, 256, 0, stream>>>(batch, gstart, N, G);
    pool_kernel<<<G, 128, 0, stream>>>(Bf, gstart, Mg);
    head1<<<G, 256, 0, stream>>>(Mg, Wh1, bh1, Gh);
    head2<<<G, 128, 0, stream>>>(Gh, Wh2, bh2, (float*)d_out);
}

// Round 3
// 497.660 us; speedup vs baseline: 1.2273x; 1.0345x over previous
//
#include <hip/hip_runtime.h>

// ---------------- CSR construction ----------------

__global__ void count_kernel(const int* __restrict__ dst, int* __restrict__ cnt, int E) {
    int e = blockIdx.x * blockDim.x + threadIdx.x;
    if (e < E) atomicAdd(&cnt[dst[e]], 1);
}

__global__ void scan1(const int* __restrict__ cnt, int* __restrict__ offs,
                      int* __restrict__ partials, int N) {
    __shared__ int s[256];
    int t = threadIdx.x;
    int i = blockIdx.x * 256 + t;
    int v = (i < N) ? cnt[i] : 0;
    s[t] = v;
    __syncthreads();
    #pragma unroll
    for (int d = 1; d < 256; d <<= 1) {
        int tv = (t >= d) ? s[t - d] : 0;
        __syncthreads();
        s[t] += tv;
        __syncthreads();
    }
    if (i < N) offs[i] = s[t] - v;   // block-local exclusive
    if (t == 255) partials[blockIdx.x] = s[255];
}

__global__ void scan2(int* partials, int nb) {
    __shared__ int s[256];
    int t = threadIdx.x;
    int v = (t < nb) ? partials[t] : 0;
    s[t] = v;
    __syncthreads();
    #pragma unroll
    for (int d = 1; d < 256; d <<= 1) {
        int tv = (t >= d) ? s[t - d] : 0;
        __syncthreads();
        s[t] += tv;
        __syncthreads();
    }
    if (t < nb) partials[t] = s[t] - v;  // exclusive block bases
}

__global__ void scan3(const int* __restrict__ cnt, int* __restrict__ offs,
                      int* __restrict__ offwork, float* __restrict__ dinv,
                      const int* __restrict__ partials, int N, int E) {
    int i = blockIdx.x * 256 + threadIdx.x;
    if (i < N) {
        int o = offs[i] + partials[blockIdx.x];
        offs[i] = o;
        offwork[i] = o;
        dinv[i] = rsqrtf((float)cnt[i] + 1.0f);  // deg = in-degree + self-loop
    }
    if (i == 0) offs[N] = E;
}

__global__ void scatter_kernel(const int* __restrict__ src, const int* __restrict__ dst,
                               int* __restrict__ offwork, int* __restrict__ csr, int E) {
    int e = blockIdx.x * blockDim.x + threadIdx.x;
    if (e < E) {
        int pos = atomicAdd(&offwork[dst[e]], 1);
        csr[pos] = src[e];
    }
}

// ---------------- fp32 GEMM: Y[M,128] = X[M,128] @ W[128,128] (+bias, relu, rowscale) ----
// BM=64, BN=128, BK=32, 256 threads, thread tile 4 rows x 8 cols.

__global__ __launch_bounds__(256, 2) void gemm128(const float* __restrict__ X,
                                                  const float* __restrict__ W,
                                                  const float* __restrict__ bias,
                                                  const float* __restrict__ rowscale,
                                                  float* __restrict__ Y,
                                                  int M, int relu) {
    __shared__ float As[32][68];    // k-major: As[k][row]
    __shared__ float Bs[32][132];   // Bs[k][col]

    int tid = threadIdx.x;
    int tx = tid & 15;       // col group 0..15
    int ty = tid >> 4;       // row group 0..15
    int row0 = blockIdx.x * 64;

    float acc[4][8];
    #pragma unroll
    for (int r = 0; r < 4; r++)
        #pragma unroll
        for (int c = 0; c < 8; c++) acc[r][c] = 0.0f;

    int lr = tid >> 2;            // 0..63: X tile row
    int kc = (tid & 3) * 8;       // k chunk within tile
    int wr = tid >> 3;            // 0..31: W k-row
    int wc = (tid & 7) * 16;      // W col chunk

    for (int k0 = 0; k0 < 128; k0 += 32) {
        float4 xa, xb;
        int grow = row0 + lr;
        if (grow < M) {
            xa = *(const float4*)&X[grow * 128 + k0 + kc];
            xb = *(const float4*)&X[grow * 128 + k0 + kc + 4];
        } else {
            xa = make_float4(0.f, 0.f, 0.f, 0.f);
            xb = make_float4(0.f, 0.f, 0.f, 0.f);
        }
        float4 w0 = *(const float4*)&W[(k0 + wr) * 128 + wc + 0];
        float4 w1 = *(const float4*)&W[(k0 + wr) * 128 + wc + 4];
        float4 w2 = *(const float4*)&W[(k0 + wr) * 128 + wc + 8];
        float4 w3 = *(const float4*)&W[(k0 + wr) * 128 + wc + 12];

        __syncthreads();
        As[kc + 0][lr] = xa.x; As[kc + 1][lr] = xa.y;
        As[kc + 2][lr] = xa.z; As[kc + 3][lr] = xa.w;
        As[kc + 4][lr] = xb.x; As[kc + 5][lr] = xb.y;
        As[kc + 6][lr] = xb.z; As[kc + 7][lr] = xb.w;
        *(float4*)&Bs[wr][wc + 0]  = w0;
        *(float4*)&Bs[wr][wc + 4]  = w1;
        *(float4*)&Bs[wr][wc + 8]  = w2;
        *(float4*)&Bs[wr][wc + 12] = w3;
        __syncthreads();

        #pragma unroll
        for (int k = 0; k < 32; k++) {
            float4 a   = *(const float4*)&As[k][ty * 4];
            float4 bb0 = *(const float4*)&Bs[k][tx * 4];
            float4 bb1 = *(const float4*)&Bs[k][64 + tx * 4];
            float av[4] = {a.x, a.y, a.z, a.w};
            float bv[8] = {bb0.x, bb0.y, bb0.z, bb0.w, bb1.x, bb1.y, bb1.z, bb1.w};
            #pragma unroll
            for (int r = 0; r < 4; r++)
                #pragma unroll
                for (int c = 0; c < 8; c++)
                    acc[r][c] = fmaf(av[r], bv[c], acc[r][c]);
        }
    }

    #pragma unroll
    for (int r = 0; r < 4; r++) {
        int grow = row0 + ty * 4 + r;
        if (grow < M) {
            float scale = rowscale ? rowscale[grow] : 1.0f;
            float o[8];
            #pragma unroll
            for (int c = 0; c < 8; c++) o[c] = acc[r][c];
            if (bias) {
                #pragma unroll
                for (int c = 0; c < 4; c++) {
                    o[c]     += bias[tx * 4 + c];
                    o[c + 4] += bias[64 + tx * 4 + c];
                }
            }
            #pragma unroll
            for (int c = 0; c < 8; c++) o[c] *= scale;
            if (relu) {
                #pragma unroll
                for (int c = 0; c < 8; c++) o[c] = fmaxf(o[c], 0.0f);
            }
            float4 o0 = make_float4(o[0], o[1], o[2], o[3]);
            float4 o1 = make_float4(o[4], o[5], o[6], o[7]);
            *(float4*)&Y[grow * 128 + tx * 4]      = o0;
            *(float4*)&Y[grow * 128 + 64 + tx * 4] = o1;
        }
    }
}

// ---------------- aggregations: 1 wave per node, float2 per lane ----------------
// Block = 128 threads = 2 waves = 2 nodes. Lane reads 8B -> 64 lanes cover 512B row.

__global__ void gcn_agg(const float* __restrict__ A, float* __restrict__ B,
                        const int* __restrict__ offs, const int* __restrict__ csr,
                        const float* __restrict__ dinv, const float* __restrict__ b0,
                        int N) {
    int v = blockIdx.x * 2 + (threadIdx.x >> 6);
    if (v >= N) return;
    int lane = threadIdx.x & 63;
    const float2* Ap = (const float2*)A;
    float2 acc = Ap[v * 64 + lane];
    int i0 = offs[v], i1 = offs[v + 1];
    int i = i0;
    for (; i + 8 <= i1; i += 8) {
        int s0 = csr[i + 0], s1 = csr[i + 1], s2 = csr[i + 2], s3 = csr[i + 3];
        int s4 = csr[i + 4], s5 = csr[i + 5], s6 = csr[i + 6], s7 = csr[i + 7];
        float2 a0 = Ap[s0 * 64 + lane], a1 = Ap[s1 * 64 + lane];
        float2 a2 = Ap[s2 * 64 + lane], a3 = Ap[s3 * 64 + lane];
        float2 a4 = Ap[s4 * 64 + lane], a5 = Ap[s5 * 64 + lane];
        float2 a6 = Ap[s6 * 64 + lane], a7 = Ap[s7 * 64 + lane];
        acc.x += a0.x + a1.x + a2.x + a3.x + a4.x + a5.x + a6.x + a7.x;
        acc.y += a0.y + a1.y + a2.y + a3.y + a4.y + a5.y + a6.y + a7.y;
    }
    for (; i + 4 <= i1; i += 4) {
        int s0 = csr[i + 0], s1 = csr[i + 1], s2 = csr[i + 2], s3 = csr[i + 3];
        float2 a0 = Ap[s0 * 64 + lane], a1 = Ap[s1 * 64 + lane];
        float2 a2 = Ap[s2 * 64 + lane], a3 = Ap[s3 * 64 + lane];
        acc.x += a0.x + a1.x + a2.x + a3.x;
        acc.y += a0.y + a1.y + a2.y + a3.y;
    }
    for (; i < i1; i++) {
        float2 a = Ap[csr[i] * 64 + lane];
        acc.x += a.x;
        acc.y += a.y;
    }
    float dv = dinv[v];
    float2 bb = ((const float2*)b0)[lane];
    float2 r;
    r.x = fmaxf(acc.x * dv + bb.x, 0.0f);
    r.y = fmaxf(acc.y * dv + bb.y, 0.0f);
    ((float2*)B)[v * 64 + lane] = r;
}

__global__ void gin_agg(const float* __restrict__ H, float* __restrict__ U,
                        const int* __restrict__ offs, const int* __restrict__ csr,
                        int N) {
    int v = blockIdx.x * 2 + (threadIdx.x >> 6);
    if (v >= N) return;
    int lane = threadIdx.x & 63;
    const float2* Hp = (const float2*)H;
    float2 acc = Hp[v * 64 + lane];
    int i0 = offs[v], i1 = offs[v + 1];
    int i = i0;
    for (; i + 8 <= i1; i += 8) {
        int s0 = csr[i + 0], s1 = csr[i + 1], s2 = csr[i + 2], s3 = csr[i + 3];
        int s4 = csr[i + 4], s5 = csr[i + 5], s6 = csr[i + 6], s7 = csr[i + 7];
        float2 a0 = Hp[s0 * 64 + lane], a1 = Hp[s1 * 64 + lane];
        float2 a2 = Hp[s2 * 64 + lane], a3 = Hp[s3 * 64 + lane];
        float2 a4 = Hp[s4 * 64 + lane], a5 = Hp[s5 * 64 + lane];
        float2 a6 = Hp[s6 * 64 + lane], a7 = Hp[s7 * 64 + lane];
        acc.x += a0.x + a1.x + a2.x + a3.x + a4.x + a5.x + a6.x + a7.x;
        acc.y += a0.y + a1.y + a2.y + a3.y + a4.y + a5.y + a6.y + a7.y;
    }
    for (; i + 4 <= i1; i += 4) {
        int s0 = csr[i + 0], s1 = csr[i + 1], s2 = csr[i + 2], s3 = csr[i + 3];
        float2 a0 = Hp[s0 * 64 + lane], a1 = Hp[s1 * 64 + lane];
        float2 a2 = Hp[s2 * 64 + lane], a3 = Hp[s3 * 64 + lane];
        acc.x += a0.x + a1.x + a2.x + a3.x;
        acc.y += a0.y + a1.y + a2.y + a3.y;
    }
    for (; i < i1; i++) {
        float2 a = Hp[csr[i] * 64 + lane];
        acc.x += a.x;
        acc.y += a.y;
    }
    ((float2*)U)[v * 64 + lane] = acc;
}

// ---------------- pooling + head ----------------

__global__ void graph_bounds(const int* __restrict__ batch, int* __restrict__ gstart,
                             int N, int G) {
    int g = blockIdx.x * blockDim.x + threadIdx.x;
    if (g > G) return;
    int lo = 0, hi = N;
    while (lo < hi) {
        int mid = (lo + hi) >> 1;
        if (batch[mid] < g) lo = mid + 1; else hi = mid;
    }
    gstart[g] = lo;
}

// Partial pooled sums: each block scans 128 sorted rows, run-length segments by
// graph id, one atomicAdd per (segment, feature).
__global__ void pool_partial(const float* __restrict__ H, const int* __restrict__ batch,
                             float* __restrict__ S, int N) {
    int r0 = blockIdx.x * 128;
    int r1 = min(r0 + 128, N);
    if (r0 >= N) return;
    int t = threadIdx.x;  // 128 threads, one feature each
    float acc = 0.0f;
    int curg = batch[r0];
    for (int r = r0; r < r1; r++) {
        int g = batch[r];
        if (g != curg) {
            atomicAdd(&S[curg * 128 + t], acc);
            acc = 0.0f;
            curg = g;
        }
        acc += H[r * 128 + t];
    }
    atomicAdd(&S[curg * 128 + t], acc);
}

// g = relu((S[g]/cnt) @ Wh1 + bh1):  [G,128] @ [128,256]
__global__ void head1(const float* __restrict__ S, const int* __restrict__ gstart,
                      const float* __restrict__ W, const float* __restrict__ b,
                      float* __restrict__ Y) {
    __shared__ float m[128];
    int g = blockIdx.x;
    int j = threadIdx.x;  // 256
    int n = gstart[g + 1] - gstart[g];
    float inv = 1.0f / (float)(n > 0 ? n : 1);
    if (j < 128) m[j] = S[g * 128 + j] * inv;
    __syncthreads();
    float acc = b[j];
    #pragma unroll 8
    for (int k = 0; k < 128; k++) acc = fmaf(m[k], W[k * 256 + j], acc);
    Y[g * 256 + j] = fmaxf(acc, 0.0f);
}

// out = g @ Wh2 + bh2:  [G,256] @ [256,128]
__global__ void head2(const float* __restrict__ Gx, const float* __restrict__ W,
                      const float* __restrict__ b, float* __restrict__ out) {
    __shared__ float m[256];
    int g = blockIdx.x;
    int j = threadIdx.x;  // 128
    m[j] = Gx[g * 256 + j];
    m[j + 128] = Gx[g * 256 + 128 + j];
    __syncthreads();
    float acc = b[j];
    #pragma unroll 8
    for (int k = 0; k < 256; k++) acc = fmaf(m[k], W[k * 128 + j], acc);
    out[g * 128 + j] = acc;
}

// ---------------- launch ----------------

extern "C" void kernel_launch(void* const* d_in, const int* in_sizes, int n_in,
                              void* d_out, int out_size, void* d_ws, size_t ws_size,
                              hipStream_t stream) {
    const float* x     = (const float*)d_in[0];
    const int*   ei    = (const int*)d_in[1];
    const int*   batch = (const int*)d_in[2];
    const float* W0  = (const float*)d_in[3];
    const float* b0  = (const float*)d_in[4];
    const float* Wg1 = (const float*)d_in[5];
    const float* bg1 = (const float*)d_in[6];
    const float* Wg2 = (const float*)d_in[7];
    const float* bg2 = (const float*)d_in[8];
    const float* Wh1 = (const float*)d_in[9];
    const float* bh1 = (const float*)d_in[10];
    const float* Wh2 = (const float*)d_in[11];
    const float* bh2 = (const float*)d_in[12];

    int N = in_sizes[2];          // batch has N elements
    int E = in_sizes[1] / 2;      // edge_index is (2,E)
    int G = out_size / 128;       // output is (G, 128)
    const int* srcp = ei;
    const int* dstp = ei + E;

    // workspace carve (256B aligned)
    char* w = (char*)d_ws;
    auto take = [&](size_t bytes) -> void* {
        void* p = (void*)w;
        w += (bytes + 255) & ~(size_t)255;
        return p;
    };
    float* A        = (float*)take((size_t)N * 128 * 4);
    float* Bf       = (float*)take((size_t)N * 128 * 4);
    int*   csr      = (int*)take((size_t)E * 4);
    int*   offs     = (int*)take((size_t)(N + 1) * 4);
    int*   offw     = (int*)take((size_t)N * 4);
    int*   cnt      = (int*)take((size_t)N * 4);
    float* dinv     = (float*)take((size_t)N * 4);
    int*   partials = (int*)take(1024);
    int*   gstart   = (int*)take((size_t)(G + 1) * 4);
    float* S        = (float*)take((size_t)G * 128 * 4);
    float* Gh       = (float*)take((size_t)G * 256 * 4);

    int nb = (N + 255) / 256;

    // CSR build
    hipMemsetAsync(cnt, 0, (size_t)N * 4, stream);
    hipMemsetAsync(S, 0, (size_t)G * 128 * 4, stream);
    count_kernel<<<(E + 255) / 256, 256, 0, stream>>>(dstp, cnt, E);
    scan1<<<nb, 256, 0, stream>>>(cnt, offs, partials, N);
    scan2<<<1, 256, 0, stream>>>(partials, nb);
    scan3<<<nb, 256, 0, stream>>>(cnt, offs, offw, dinv, partials, N, E);
    scatter_kernel<<<(E + 255) / 256, 256, 0, stream>>>(srcp, dstp, offw, csr, E);

    // GCN: A = (x@W0) * dinv[row] ; B = relu((A[v]+sum A[nbr]) * dinv[v] + b0)
    gemm128<<<(N + 63) / 64, 256, 0, stream>>>(x, W0, nullptr, dinv, A, N, 0);
    gcn_agg<<<(N + 1) / 2, 128, 0, stream>>>(A, Bf, offs, csr, dinv, b0, N);

    // GIN 1
    gin_agg<<<(N + 1) / 2, 128, 0, stream>>>(Bf, A, offs, csr, N);
    gemm128<<<(N + 63) / 64, 256, 0, stream>>>(A, Wg1, bg1, nullptr, Bf, N, 1);

    // GIN 2
    gin_agg<<<(N + 1) / 2, 128, 0, stream>>>(Bf, A, offs, csr, N);
    gemm128<<<(N + 63) / 64, 256, 0, stream>>>(A, Wg2, bg2, nullptr, Bf, N, 1);

    // pool + head
    graph_bounds<<<(G + 1 + 255) / 256, 256, 0, stream>>>(batch, gstart, N, G);
    pool_partial<<<(N + 127) / 128, 128, 0, stream>>>(Bf, batch, S, N);
    head1<<<G, 256, 0, stream>>>(S, gstart, Wh1, bh1, Gh);
    head2<<<G, 128, 0, stream>>>(Gh, Wh2, bh2, (float*)d_out);
}

// Round 7
// 490.278 us; speedup vs baseline: 1.2458x; 1.0151x over previous
//
#include <hip/hip_runtime.h>

// ---------------- CSR construction ----------------

__global__ void count_kernel(const int* __restrict__ dst, int* __restrict__ cnt, int E) {
    int e = blockIdx.x * blockDim.x + threadIdx.x;
    if (e < E) atomicAdd(&cnt[dst[e]], 1);
}

__global__ void scan1(const int* __restrict__ cnt, int* __restrict__ offs,
                      int* __restrict__ partials, int N) {
    __shared__ int s[256];
    int t = threadIdx.x;
    int i = blockIdx.x * 256 + t;
    int v = (i < N) ? cnt[i] : 0;
    s[t] = v;
    __syncthreads();
    #pragma unroll
    for (int d = 1; d < 256; d <<= 1) {
        int tv = (t >= d) ? s[t - d] : 0;
        __syncthreads();
        s[t] += tv;
        __syncthreads();
    }
    if (i < N) offs[i] = s[t] - v;   // block-local exclusive
    if (t == 255) partials[blockIdx.x] = s[255];
}

__global__ void scan2(int* partials, int nb) {
    __shared__ int s[256];
    int t = threadIdx.x;
    int v = (t < nb) ? partials[t] : 0;
    s[t] = v;
    __syncthreads();
    #pragma unroll
    for (int d = 1; d < 256; d <<= 1) {
        int tv = (t >= d) ? s[t - d] : 0;
        __syncthreads();
        s[t] += tv;
        __syncthreads();
    }
    if (t < nb) partials[t] = s[t] - v;  // exclusive block bases
}

__global__ void scan3(const int* __restrict__ cnt, int* __restrict__ offs,
                      int* __restrict__ offwork, float* __restrict__ dinv,
                      const int* __restrict__ partials, int N, int E) {
    int i = blockIdx.x * 256 + threadIdx.x;
    if (i < N) {
        int o = offs[i] + partials[blockIdx.x];
        offs[i] = o;
        offwork[i] = o;
        dinv[i] = rsqrtf((float)cnt[i] + 1.0f);  // deg = in-degree + self-loop
    }
    if (i == 0) offs[N] = E;
}

__global__ void scatter_kernel(const int* __restrict__ src, const int* __restrict__ dst,
                               int* __restrict__ offwork, int* __restrict__ csr, int E) {
    int e = blockIdx.x * blockDim.x + threadIdx.x;
    if (e < E) {
        int pos = atomicAdd(&offwork[dst[e]], 1);
        csr[pos] = src[e];
    }
}

// ---------------- fp32 GEMM: Y[M,128] = X[M,128] @ W[128,128] (+bias, relu, rowscale) ----
// BM=64, BN=128, BK=32, 256 threads, thread tile 4 rows x 8 cols.

__global__ __launch_bounds__(256, 2) void gemm128(const float* __restrict__ X,
                                                  const float* __restrict__ W,
                                                  const float* __restrict__ bias,
                                                  const float* __restrict__ rowscale,
                                                  float* __restrict__ Y,
                                                  int M, int relu) {
    __shared__ float As[32][68];    // k-major: As[k][row]
    __shared__ float Bs[32][132];   // Bs[k][col]

    int tid = threadIdx.x;
    int tx = tid & 15;       // col group 0..15
    int ty = tid >> 4;       // row group 0..15
    int row0 = blockIdx.x * 64;

    float acc[4][8];
    #pragma unroll
    for (int r = 0; r < 4; r++)
        #pragma unroll
        for (int c = 0; c < 8; c++) acc[r][c] = 0.0f;

    int lr = tid >> 2;            // 0..63: X tile row
    int kc = (tid & 3) * 8;       // k chunk within tile
    int wr = tid >> 3;            // 0..31: W k-row
    int wc = (tid & 7) * 16;      // W col chunk

    for (int k0 = 0; k0 < 128; k0 += 32) {
        float4 xa, xb;
        int grow = row0 + lr;
        if (grow < M) {
            xa = *(const float4*)&X[grow * 128 + k0 + kc];
            xb = *(const float4*)&X[grow * 128 + k0 + kc + 4];
        } else {
            xa = make_float4(0.f, 0.f, 0.f, 0.f);
            xb = make_float4(0.f, 0.f, 0.f, 0.f);
        }
        float4 w0 = *(const float4*)&W[(k0 + wr) * 128 + wc + 0];
        float4 w1 = *(const float4*)&W[(k0 + wr) * 128 + wc + 4];
        float4 w2 = *(const float4*)&W[(k0 + wr) * 128 + wc + 8];
        float4 w3 = *(const float4*)&W[(k0 + wr) * 128 + wc + 12];

        __syncthreads();
        As[kc + 0][lr] = xa.x; As[kc + 1][lr] = xa.y;
        As[kc + 2][lr] = xa.z; As[kc + 3][lr] = xa.w;
        As[kc + 4][lr] = xb.x; As[kc + 5][lr] = xb.y;
        As[kc + 6][lr] = xb.z; As[kc + 7][lr] = xb.w;
        *(float4*)&Bs[wr][wc + 0]  = w0;
        *(float4*)&Bs[wr][wc + 4]  = w1;
        *(float4*)&Bs[wr][wc + 8]  = w2;
        *(float4*)&Bs[wr][wc + 12] = w3;
        __syncthreads();

        #pragma unroll
        for (int k = 0; k < 32; k++) {
            float4 a   = *(const float4*)&As[k][ty * 4];
            float4 bb0 = *(const float4*)&Bs[k][tx * 4];
            float4 bb1 = *(const float4*)&Bs[k][64 + tx * 4];
            float av[4] = {a.x, a.y, a.z, a.w};
            float bv[8] = {bb0.x, bb0.y, bb0.z, bb0.w, bb1.x, bb1.y, bb1.z, bb1.w};
            #pragma unroll
            for (int r = 0; r < 4; r++)
                #pragma unroll
                for (int c = 0; c < 8; c++)
                    acc[r][c] = fmaf(av[r], bv[c], acc[r][c]);
        }
    }

    #pragma unroll
    for (int r = 0; r < 4; r++) {
        int grow = row0 + ty * 4 + r;
        if (grow < M) {
            float scale = rowscale ? rowscale[grow] : 1.0f;
            float o[8];
            #pragma unroll
            for (int c = 0; c < 8; c++) o[c] = acc[r][c];
            if (bias) {
                #pragma unroll
                for (int c = 0; c < 4; c++) {
                    o[c]     += bias[tx * 4 + c];
                    o[c + 4] += bias[64 + tx * 4 + c];
                }
            }
            #pragma unroll
            for (int c = 0; c < 8; c++) o[c] *= scale;
            if (relu) {
                #pragma unroll
                for (int c = 0; c < 8; c++) o[c] = fmaxf(o[c], 0.0f);
            }
            float4 o0 = make_float4(o[0], o[1], o[2], o[3]);
            float4 o1 = make_float4(o[4], o[5], o[6], o[7]);
            *(float4*)&Y[grow * 128 + tx * 4]      = o0;
            *(float4*)&Y[grow * 128 + 64 + tx * 4] = o1;
        }
    }
}

// ---------------- aggregation: 1 wave per node, float4 per lane-half ----------------
// Lanes 0-31 cover the 512B row (32 x float4) for EVEN neighbors, lanes 32-63 for
// ODD neighbors (same list -> no divergence). Combine halves with shfl_xor(32).
// mode 0: U[v] = H[v] + sum H[nbr]           (GIN pre-linear)
// mode 1: B[v] = relu((A[v]+sum A[nbr])*dinv[v] + b0)   (GCN, A pre-scaled by dinv)

__global__ __launch_bounds__(256) void agg_kernel(const float* __restrict__ A,
                                                  float* __restrict__ B,
                                                  const int* __restrict__ offs,
                                                  const int* __restrict__ csr,
                                                  const float* __restrict__ dinv,
                                                  const float* __restrict__ b0,
                                                  int N, int mode) {
    int v = blockIdx.x * 4 + (threadIdx.x >> 6);
    if (v >= N) return;
    int lane = threadIdx.x & 63;
    int half = lane >> 5;
    int l32 = lane & 31;
    const float4* Ap = (const float4*)A;

    float4 acc;
    if (half == 0) {
        acc = Ap[(size_t)v * 32 + l32];       // self term counted once
    } else {
        acc = make_float4(0.f, 0.f, 0.f, 0.f);
    }

    int i0 = offs[v], i1 = offs[v + 1];
    int p = i0 + half;                        // this half's first neighbor, stride 2
    // 4 neighbors per half per iteration -> 8 total, 64B/lane in flight
    for (; p + 6 < i1; p += 8) {
        int s0 = csr[p + 0];
        int s1 = csr[p + 2];
        int s2 = csr[p + 4];
        int s3 = csr[p + 6];
        float4 a0 = Ap[(size_t)s0 * 32 + l32];
        float4 a1 = Ap[(size_t)s1 * 32 + l32];
        float4 a2 = Ap[(size_t)s2 * 32 + l32];
        float4 a3 = Ap[(size_t)s3 * 32 + l32];
        acc.x += a0.x + a1.x + a2.x + a3.x;
        acc.y += a0.y + a1.y + a2.y + a3.y;
        acc.z += a0.z + a1.z + a2.z + a3.z;
        acc.w += a0.w + a1.w + a2.w + a3.w;
    }
    for (; p < i1; p += 2) {
        float4 a = Ap[(size_t)csr[p] * 32 + l32];
        acc.x += a.x; acc.y += a.y; acc.z += a.z; acc.w += a.w;
    }

    // combine even/odd halves (lane i <-> lane i^32)
    acc.x += __shfl_xor(acc.x, 32, 64);
    acc.y += __shfl_xor(acc.y, 32, 64);
    acc.z += __shfl_xor(acc.z, 32, 64);
    acc.w += __shfl_xor(acc.w, 32, 64);

    if (half == 0) {
        float4 r = acc;
        if (mode == 1) {
            float dv = dinv[v];
            float4 bb = ((const float4*)b0)[l32];
            r.x = fmaxf(r.x * dv + bb.x, 0.0f);
            r.y = fmaxf(r.y * dv + bb.y, 0.0f);
            r.z = fmaxf(r.z * dv + bb.z, 0.0f);
            r.w = fmaxf(r.w * dv + bb.w, 0.0f);
        }
        ((float4*)B)[(size_t)v * 32 + l32] = r;
    }
}

// ---------------- pooling + head ----------------

// Partial pooled sums: each block scans 128 sorted rows, run-length segments by
// graph id, one atomicAdd per (segment, feature).
__global__ void pool_partial(const float* __restrict__ H, const int* __restrict__ batch,
                             float* __restrict__ S, int N) {
    int r0 = blockIdx.x * 128;
    int r1 = min(r0 + 128, N);
    if (r0 >= N) return;
    int t = threadIdx.x;  // 128 threads, one feature each
    float acc = 0.0f;
    int curg = batch[r0];
    for (int r = r0; r < r1; r++) {
        int g = batch[r];
        if (g != curg) {
            atomicAdd(&S[curg * 128 + t], acc);
            acc = 0.0f;
            curg = g;
        }
        acc += H[r * 128 + t];
    }
    atomicAdd(&S[curg * 128 + t], acc);
}

// g = relu((S[g]/cnt) @ Wh1 + bh1):  [G,128] @ [128,256]; graph bounds inlined.
__global__ void head1(const float* __restrict__ S, const int* __restrict__ batch,
                      const float* __restrict__ W, const float* __restrict__ b,
                      float* __restrict__ Y, int N, int G) {
    __shared__ float m[128];
    __shared__ int bound[2];
    int g = blockIdx.x;
    int j = threadIdx.x;  // 256
    if (j < 2) {
        int target = g + j;
        int lo = 0, hi = N;
        while (lo < hi) {
            int mid = (lo + hi) >> 1;
            if (batch[mid] < target) lo = mid + 1; else hi = mid;
        }
        bound[j] = lo;
    }
    __syncthreads();
    int n = bound[1] - bound[0];
    float inv = 1.0f / (float)(n > 0 ? n : 1);
    if (j < 128) m[j] = S[g * 128 + j] * inv;
    __syncthreads();
    float acc = b[j];
    #pragma unroll 8
    for (int k = 0; k < 128; k++) acc = fmaf(m[k], W[k * 256 + j], acc);
    Y[g * 256 + j] = fmaxf(acc, 0.0f);
}

// out = g @ Wh2 + bh2:  [G,256] @ [256,128]
__global__ void head2(const float* __restrict__ Gx, const float* __restrict__ W,
                      const float* __restrict__ b, float* __restrict__ out) {
    __shared__ float m[256];
    int g = blockIdx.x;
    int j = threadIdx.x;  // 128
    m[j] = Gx[g * 256 + j];
    m[j + 128] = Gx[g * 256 + 128 + j];
    __syncthreads();
    float acc = b[j];
    #pragma unroll 8
    for (int k = 0; k < 256; k++) acc = fmaf(m[k], W[k * 128 + j], acc);
    out[g * 128 + j] = acc;
}

// ---------------- launch ----------------

extern "C" void kernel_launch(void* const* d_in, const int* in_sizes, int n_in,
                              void* d_out, int out_size, void* d_ws, size_t ws_size,
                              hipStream_t stream) {
    const float* x     = (const float*)d_in[0];
    const int*   ei    = (const int*)d_in[1];
    const int*   batch = (const int*)d_in[2];
    const float* W0  = (const float*)d_in[3];
    const float* b0  = (const float*)d_in[4];
    const float* Wg1 = (const float*)d_in[5];
    const float* bg1 = (const float*)d_in[6];
    const float* Wg2 = (const float*)d_in[7];
    const float* bg2 = (const float*)d_in[8];
    const float* Wh1 = (const float*)d_in[9];
    const float* bh1 = (const float*)d_in[10];
    const float* Wh2 = (const float*)d_in[11];
    const float* bh2 = (const float*)d_in[12];

    int N = in_sizes[2];          // batch has N elements
    int E = in_sizes[1] / 2;      // edge_index is (2,E)
    int G = out_size / 128;       // output is (G, 128)
    const int* srcp = ei;
    const int* dstp = ei + E;

    // workspace carve (256B aligned)
    char* w = (char*)d_ws;
    auto take = [&](size_t bytes) -> void* {
        void* p = (void*)w;
        w += (bytes + 255) & ~(size_t)255;
        return p;
    };
    float* A        = (float*)take((size_t)N * 128 * 4);
    float* Bf       = (float*)take((size_t)N * 128 * 4);
    int*   csr      = (int*)take((size_t)E * 4);
    int*   offs     = (int*)take((size_t)(N + 1) * 4);
    int*   offw     = (int*)take((size_t)N * 4);
    int*   cnt      = (int*)take((size_t)N * 4);
    float* dinv     = (float*)take((size_t)N * 4);
    int*   partials = (int*)take(1024);
    float* S        = (float*)take((size_t)G * 128 * 4);
    float* Gh       = (float*)take((size_t)G * 256 * 4);

    int nb = (N + 255) / 256;

    // CSR build
    hipMemsetAsync(cnt, 0, (size_t)N * 4, stream);
    hipMemsetAsync(S, 0, (size_t)G * 128 * 4, stream);
    count_kernel<<<(E + 255) / 256, 256, 0, stream>>>(dstp, cnt, E);
    scan1<<<nb, 256, 0, stream>>>(cnt, offs, partials, N);
    scan2<<<1, 256, 0, stream>>>(partials, nb);
    scan3<<<nb, 256, 0, stream>>>(cnt, offs, offw, dinv, partials, N, E);
    scatter_kernel<<<(E + 255) / 256, 256, 0, stream>>>(srcp, dstp, offw, csr, E);

    // GCN: A = (x@W0) * dinv[row] ; B = relu((A[v]+sum A[nbr]) * dinv[v] + b0)
    gemm128<<<(N + 63) / 64, 256, 0, stream>>>(x, W0, nullptr, dinv, A, N, 0);
    agg_kernel<<<(N + 3) / 4, 256, 0, stream>>>(A, Bf, offs, csr, dinv, b0, N, 1);

    // GIN 1
    agg_kernel<<<(N + 3) / 4, 256, 0, stream>>>(Bf, A, offs, csr, nullptr, nullptr, N, 0);
    gemm128<<<(N + 63) / 64, 256, 0, stream>>>(A, Wg1, bg1, nullptr, Bf, N, 1);

    // GIN 2
    agg_kernel<<<(N + 3) / 4, 256, 0, stream>>>(Bf, A, offs, csr, nullptr, nullptr, N, 0);
    gemm128<<<(N + 63) / 64, 256, 0, stream>>>(A, Wg2, bg2, nullptr, Bf, N, 1);

    // pool + head
    pool_partial<<<(N + 127) / 128, 128, 0, stream>>>(Bf, batch, S, N);
    head1<<<G, 256, 0, stream>>>(S, batch, Wh1, bh1, Gh, N, G);
    head2<<<G, 128, 0, stream>>>(Gh, Wh2, bh2, (float*)d_out);
}